// Round 5
// baseline (232.219 us; speedup 1.0000x reference)
//
#include <hip/hip_runtime.h>
#include <hip/hip_bf16.h>
#include <stdint.h>

#define NN 32768
#define KK 1024
#define DD 256
#define BM 32
#define CHUNK 128
#define NCHUNK (KK / CHUNK)   // 8
#define NTHR 512

// LDS byte offsets: Xs 16KB @0 | Ps 64KB @16384 | total 80KB -> 2 blocks/CU.
// Row-stat scratch reuses the Xs region after the MFMA loop (barrier-guarded).
#define LXS 0
#define LPS 16384
#define LTOT 81920
#define SC_MAXP 0        // [32 rows][8 waves] {f32 max, i32 argmax} = 2048 B
#define SC_M    2048     // [32] f32 final max
#define SC_MI   2176     // [32] i32 final argmax
#define SC_ZP   2304     // [32][8] f32 sumexp partials = 1024 B
#define SC_LZ   3328     // [32] f32 logZ

// ws layout (floats): [0,1024) np2 | [1024,2048) colsum_y | [2048,3072) colsum_lp
// | bytes [12288, 12288+524288) Pbf16 (fast path)

typedef __attribute__((ext_vector_type(8))) short bf16x8;
typedef __attribute__((ext_vector_type(4))) float f32x4;

__device__ __forceinline__ uint32_t pkbf2(float a, float b) {  // RNE f32->bf16 pack
    uint32_t ua = __builtin_bit_cast(uint32_t, a);
    uint32_t ub = __builtin_bit_cast(uint32_t, b);
    ua = (ua + 0x7fffu + ((ua >> 16) & 1u)) >> 16;
    ub = (ub + 0x7fffu + ((ub >> 16) & 1u)) >> 16;
    return ua | (ub << 16);
}
__device__ __forceinline__ float ubf(uint32_t h) {  // bf16 bits -> f32 (exact)
    return __builtin_bit_cast(float, h << 16);
}

__global__ void vq_init(const float* __restrict__ protos, float* __restrict__ ws) {
    int k = blockIdx.x * 256 + threadIdx.x;   // grid 4 x 256 -> 1024 protos
    const float4* p4 = reinterpret_cast<const float4*>(protos + (size_t)k * DD);
    float s = 0.f;
#pragma unroll 8
    for (int j = 0; j < DD / 4; ++j) {
        float4 v = p4[j];
        s = fmaf(v.x, v.x, s); s = fmaf(v.y, v.y, s);
        s = fmaf(v.z, v.z, s); s = fmaf(v.w, v.w, s);
    }
    ws[k] = s;
    ws[KK + k] = 0.f;
    ws[2 * KK + k] = 0.f;
}

__global__ void vq_cvt(const float* __restrict__ protos, uint32_t* __restrict__ pb) {
    int idx = blockIdx.x * 256 + threadIdx.x;  // 0..32767, 8 floats each
    const float4* s = reinterpret_cast<const float4*>(protos + (size_t)idx * 8);
    float4 a = s[0], b = s[1];
    uint4 v;
    v.x = pkbf2(a.x, a.y); v.y = pkbf2(a.z, a.w);
    v.z = pkbf2(b.x, b.y); v.w = pkbf2(b.z, b.w);
    reinterpret_cast<uint4*>(pb)[idx] = v;
}

template<bool PRE>
__global__ __launch_bounds__(NTHR, 4) void vq_mainT(const float* __restrict__ latents,
                                                    const float* __restrict__ protos,
                                                    const float* __restrict__ gumbel,
                                                    float* __restrict__ ws,
                                                    float* __restrict__ out) {
    __shared__ __align__(16) unsigned char sm[LTOT];
    const int t = threadIdx.x;
    const int lane = t & 63;
    const int w = t >> 6;                 // wave 0..7
    const int n0 = blockIdx.x * BM;
    const int l15 = lane & 15;
    const int l4 = lane >> 4;
    const float* np2 = ws;
    float* colsum_y = ws + KK;
    float* colsum_lp = ws + 2 * KK;
    const uint4* pb = reinterpret_cast<const uint4*>(ws + 3 * KK);

    // ---- stage X: 32 rows x 256 f32 -> bf16 LDS (16B-granule XOR-swizzled) ----
    {
        int row = t >> 4;
        int g0 = (t & 15) * 2;
#pragma unroll
        for (int j = 0; j < 2; ++j) {
            int g = g0 + j;
            const float4* src = reinterpret_cast<const float4*>(
                latents + (size_t)(n0 + row) * DD + g * 8);
            float4 a = src[0], b = src[1];
            uint4 v; v.x = pkbf2(a.x, a.y); v.y = pkbf2(a.z, a.w);
            v.z = pkbf2(b.x, b.y); v.w = pkbf2(b.z, b.w);
            *reinterpret_cast<uint4*>(sm + LXS + row * 512 + ((g ^ (row & 7)) << 4)) = v;
        }
    }

    const int pr = w * 16 + l15;          // proto row (local) for A-frag
    const int cwbase = w * 16 + l4 * 4;   // per-thread column base within chunk
    uint32_t Sp[32];                      // packed bf16 S: [chunk][4]

#pragma unroll
    for (int c = 0; c < NCHUNK; ++c) {
        __syncthreads();                  // prev chunk Ps reads done / Xs visible
        // ---- stage Ps: 128 protos x 256 bf16 ----
        if (PRE) {
#pragma unroll
            for (int i = 0; i < 8; ++i) {
                int G = t + NTHR * i;     // 16B-granule id, 0..4095
                int p = G >> 5, g = G & 31;
                uint4 v = pb[(size_t)(c * CHUNK + p) * 32 + g];
                *reinterpret_cast<uint4*>(sm + LPS + p * 512 + ((g ^ (p & 7)) << 4)) = v;
            }
        } else {
#pragma unroll
            for (int i = 0; i < 8; ++i) {
                int G = t + NTHR * i;
                int p = G >> 5, g = G & 31;
                const float4* src = reinterpret_cast<const float4*>(
                    protos + (size_t)(c * CHUNK + p) * DD + g * 8);
                float4 a = src[0], b = src[1];
                uint4 v; v.x = pkbf2(a.x, a.y); v.y = pkbf2(a.z, a.w);
                v.z = pkbf2(b.x, b.y); v.w = pkbf2(b.z, b.w);
                *reinterpret_cast<uint4*>(sm + LPS + p * 512 + ((g ^ (p & 7)) << 4)) = v;
            }
        }
        __syncthreads();

        // prefetch epilogue operands (hide HBM latency under MFMA)
        const int pg0 = c * CHUNK + cwbase;
        float4 q4 = *reinterpret_cast<const float4*>(np2 + pg0);
        float4 g40 = *reinterpret_cast<const float4*>(gumbel + (size_t)(n0 + l15) * KK + pg0);
        float4 g41 = *reinterpret_cast<const float4*>(gumbel + (size_t)(n0 + 16 + l15) * KK + pg0);

        f32x4 acc0 = {0.f, 0.f, 0.f, 0.f}, acc1 = {0.f, 0.f, 0.f, 0.f};
#pragma unroll
        for (int ks = 0; ks < 8; ++ks) {
            int gi = ks * 4 + l4;
            bf16x8 af = *reinterpret_cast<bf16x8*>(sm + LPS + pr * 512 + ((gi ^ (pr & 7)) << 4));
            bf16x8 b0 = *reinterpret_cast<bf16x8*>(sm + LXS + l15 * 512 + ((gi ^ (l15 & 7)) << 4));
            bf16x8 b1 = *reinterpret_cast<bf16x8*>(sm + LXS + (16 + l15) * 512 + ((gi ^ ((16 + l15) & 7)) << 4));
            acc0 = __builtin_amdgcn_mfma_f32_16x16x32_bf16(af, b0, acc0, 0, 0, 0);
            acc1 = __builtin_amdgcn_mfma_f32_16x16x32_bf16(af, b1, acc1, 0, 0, 0);
        }
        // ---- epilogue: S = 2*acc - np2 + gumbel -> packed bf16 registers ----
        Sp[c * 4 + 0] = pkbf2(fmaf(2.f, acc0.x, -q4.x) + g40.x,
                              fmaf(2.f, acc0.y, -q4.y) + g40.y);
        Sp[c * 4 + 1] = pkbf2(fmaf(2.f, acc0.z, -q4.z) + g40.z,
                              fmaf(2.f, acc0.w, -q4.w) + g40.w);
        Sp[c * 4 + 2] = pkbf2(fmaf(2.f, acc1.x, -q4.x) + g41.x,
                              fmaf(2.f, acc1.y, -q4.y) + g41.y);
        Sp[c * 4 + 3] = pkbf2(fmaf(2.f, acc1.z, -q4.z) + g41.z,
                              fmaf(2.f, acc1.w, -q4.w) + g41.w);
    }
    __syncthreads();   // all Xs/Ps reads done -> Xs region becomes scratch

    // ---- Phase B1: per-thread max/argmax over register S ----
    float m0 = -3.4e38f, m1 = -3.4e38f; int mi0 = 0, mi1 = 0;
#pragma unroll
    for (int c = 0; c < NCHUNK; ++c) {
        int cb = c * CHUNK + cwbase;
        float f;
        f = ubf(Sp[c*4+0] & 0xffffu); if (f > m0) { m0 = f; mi0 = cb; }
        f = ubf(Sp[c*4+0] >> 16);     if (f > m0) { m0 = f; mi0 = cb + 1; }
        f = ubf(Sp[c*4+1] & 0xffffu); if (f > m0) { m0 = f; mi0 = cb + 2; }
        f = ubf(Sp[c*4+1] >> 16);     if (f > m0) { m0 = f; mi0 = cb + 3; }
        f = ubf(Sp[c*4+2] & 0xffffu); if (f > m1) { m1 = f; mi1 = cb; }
        f = ubf(Sp[c*4+2] >> 16);     if (f > m1) { m1 = f; mi1 = cb + 1; }
        f = ubf(Sp[c*4+3] & 0xffffu); if (f > m1) { m1 = f; mi1 = cb + 2; }
        f = ubf(Sp[c*4+3] >> 16);     if (f > m1) { m1 = f; mi1 = cb + 3; }
    }
    // B2: reduce across l4 (lane bits 4,5); tie-break -> smallest col index
#pragma unroll
    for (int off = 16; off <= 32; off <<= 1) {
        float o0 = __shfl_xor(m0, off); int i0 = __shfl_xor(mi0, off);
        if (o0 > m0 || (o0 == m0 && i0 < mi0)) { m0 = o0; mi0 = i0; }
        float o1 = __shfl_xor(m1, off); int i1 = __shfl_xor(mi1, off);
        if (o1 > m1 || (o1 == m1 && i1 < mi1)) { m1 = o1; mi1 = i1; }
    }
    if (lane < 16) {
        *reinterpret_cast<float*>(sm + SC_MAXP + (l15 * 8 + w) * 8) = m0;
        *reinterpret_cast<int*>(sm + SC_MAXP + (l15 * 8 + w) * 8 + 4) = mi0;
        *reinterpret_cast<float*>(sm + SC_MAXP + ((16 + l15) * 8 + w) * 8) = m1;
        *reinterpret_cast<int*>(sm + SC_MAXP + ((16 + l15) * 8 + w) * 8 + 4) = mi1;
    }
    __syncthreads();
    if (t < 32) {
        float m = -3.4e38f; int mi = 0;
#pragma unroll
        for (int j = 0; j < 8; ++j) {
            float om = *reinterpret_cast<float*>(sm + SC_MAXP + (t * 8 + j) * 8);
            int oi = *reinterpret_cast<int*>(sm + SC_MAXP + (t * 8 + j) * 8 + 4);
            if (om > m || (om == m && oi < mi)) { m = om; mi = oi; }
        }
        *reinterpret_cast<float*>(sm + SC_M + t * 4) = m;
        *reinterpret_cast<int*>(sm + SC_MI + t * 4) = mi;
    }
    __syncthreads();
    // ---- Phase B5: sumexp with final max ----
    {
        float mA = *reinterpret_cast<float*>(sm + SC_M + l15 * 4);
        float mB = *reinterpret_cast<float*>(sm + SC_M + (16 + l15) * 4);
        float z0 = 0.f, z1 = 0.f;
#pragma unroll
        for (int c = 0; c < NCHUNK; ++c) {
            z0 += __expf(ubf(Sp[c*4+0] & 0xffffu) - mA) + __expf(ubf(Sp[c*4+0] >> 16) - mA)
                + __expf(ubf(Sp[c*4+1] & 0xffffu) - mA) + __expf(ubf(Sp[c*4+1] >> 16) - mA);
            z1 += __expf(ubf(Sp[c*4+2] & 0xffffu) - mB) + __expf(ubf(Sp[c*4+2] >> 16) - mB)
                + __expf(ubf(Sp[c*4+3] & 0xffffu) - mB) + __expf(ubf(Sp[c*4+3] >> 16) - mB);
        }
        z0 += __shfl_xor(z0, 16); z0 += __shfl_xor(z0, 32);
        z1 += __shfl_xor(z1, 16); z1 += __shfl_xor(z1, 32);
        if (lane < 16) {
            *reinterpret_cast<float*>(sm + SC_ZP + (l15 * 8 + w) * 4) = z0;
            *reinterpret_cast<float*>(sm + SC_ZP + ((16 + l15) * 8 + w) * 4) = z1;
        }
    }
    __syncthreads();
    if (t < 32) {
        float Z = 0.f;
#pragma unroll
        for (int j = 0; j < 8; ++j)
            Z += *reinterpret_cast<float*>(sm + SC_ZP + (t * 8 + j) * 4);
        *reinterpret_cast<float*>(sm + SC_LZ + t * 4) =
            *reinterpret_cast<float*>(sm + SC_M + t * 4) + __logf(Z);
    }
    __syncthreads();

    // ---- Phase C1: column sums (reduce across l15 lanes, atomics from l15==0) ----
    {
        float lzA = *reinterpret_cast<float*>(sm + SC_LZ + l15 * 4);
        float lzB = *reinterpret_cast<float*>(sm + SC_LZ + (16 + l15) * 4);
#pragma unroll
        for (int c = 0; c < NCHUNK; ++c) {
            float a0 = ubf(Sp[c*4+0] & 0xffffu) - lzA, a1 = ubf(Sp[c*4+0] >> 16) - lzA;
            float a2 = ubf(Sp[c*4+1] & 0xffffu) - lzA, a3 = ubf(Sp[c*4+1] >> 16) - lzA;
            float b0 = ubf(Sp[c*4+2] & 0xffffu) - lzB, b1 = ubf(Sp[c*4+2] >> 16) - lzB;
            float b2 = ubf(Sp[c*4+3] & 0xffffu) - lzB, b3 = ubf(Sp[c*4+3] >> 16) - lzB;
            float sy0 = __expf(a0) + __expf(b0), sy1 = __expf(a1) + __expf(b1);
            float sy2 = __expf(a2) + __expf(b2), sy3 = __expf(a3) + __expf(b3);
            float sl0 = a0 + b0, sl1 = a1 + b1, sl2 = a2 + b2, sl3 = a3 + b3;
#pragma unroll
            for (int off = 1; off < 16; off <<= 1) {
                sy0 += __shfl_xor(sy0, off); sy1 += __shfl_xor(sy1, off);
                sy2 += __shfl_xor(sy2, off); sy3 += __shfl_xor(sy3, off);
                sl0 += __shfl_xor(sl0, off); sl1 += __shfl_xor(sl1, off);
                sl2 += __shfl_xor(sl2, off); sl3 += __shfl_xor(sl3, off);
            }
            if (l15 == 0) {
                int cb = c * CHUNK + cwbase;
                atomicAdd(&colsum_y[cb],     sy0); atomicAdd(&colsum_y[cb + 1], sy1);
                atomicAdd(&colsum_y[cb + 2], sy2); atomicAdd(&colsum_y[cb + 3], sy3);
                atomicAdd(&colsum_lp[cb],     sl0); atomicAdd(&colsum_lp[cb + 1], sl1);
                atomicAdd(&colsum_lp[cb + 2], sl2); atomicAdd(&colsum_lp[cb + 3], sl3);
            }
        }
    }

    // ---- Phase C2: quantized = protos[argmax] (f32 gather) ----
    {
        int row = t >> 4, v = t & 15;
        int idx = *reinterpret_cast<int*>(sm + SC_MI + row * 4);
        const float4* src = reinterpret_cast<const float4*>(protos + (size_t)idx * DD + v * 16);
        float4* dst = reinterpret_cast<float4*>(out + (size_t)(n0 + row) * DD + v * 16);
#pragma unroll
        for (int j = 0; j < 4; ++j) dst[j] = src[j];
    }
}

__global__ void vq_final(const float* __restrict__ ws,
                         float* __restrict__ out, int out_size) {
    __shared__ float part[4];
    int t = threadIdx.x;  // 1 block x 256
    const float invN = 1.0f / (float)NN;
    float a = 0.f;
    for (int j = 0; j < 4; ++j) {
        int k = t + j * 256;
        float prior = fmaf(ws[KK + k], invN, 1e-6f);
        float Lk = ws[2 * KK + k] * invN;
        a += prior * (1.001f * __logf(prior) - Lk);
    }
#pragma unroll
    for (int off = 32; off >= 1; off >>= 1) a += __shfl_xor(a, off);
    if ((t & 63) == 0) part[t >> 6] = a;
    __syncthreads();
    if (t == 0) {
        out[out_size - 1] = part[0] + part[1] + part[2] + part[3];
    }
}

extern "C" void kernel_launch(void* const* d_in, const int* in_sizes, int n_in,
                              void* d_out, int out_size, void* d_ws, size_t ws_size,
                              hipStream_t stream) {
    (void)in_sizes; (void)n_in;
    const float* latents = (const float*)d_in[0];
    const float* protos  = (const float*)d_in[1];
    const float* gumbel  = (const float*)d_in[2];
    float* out           = (float*)d_out;
    float* ws            = (float*)d_ws;

    bool pre = ws_size >= (size_t)(3 * KK * 4 + KK * DD * 2);

    vq_init<<<dim3(4), dim3(256), 0, stream>>>(protos, ws);
    if (pre) {
        vq_cvt<<<dim3(KK * DD / 2048), dim3(256), 0, stream>>>(
            protos, (uint32_t*)(ws + 3 * KK));
        vq_mainT<true><<<dim3(NN / BM), dim3(NTHR), 0, stream>>>(
            latents, protos, gumbel, ws, out);
    } else {
        vq_mainT<false><<<dim3(NN / BM), dim3(NTHR), 0, stream>>>(
            latents, protos, gumbel, ws, out);
    }
    vq_final<<<dim3(1), dim3(256), 0, stream>>>(ws, out, out_size);
}